// Round 1
// baseline (378.953 us; speedup 1.0000x reference)
//
#include <hip/hip_runtime.h>
#include <math.h>

// Problem constants (fixed by the reference)
#define BB 256
#define SS 512
#define DD 7
#define ROWS 8          // query rows per block (one per wave)
#define THREADS 512     // 8 waves

__device__ __forceinline__ float wave_max(float v) {
    #pragma unroll
    for (int off = 32; off; off >>= 1) v = fmaxf(v, __shfl_xor(v, off, 64));
    return v;
}
__device__ __forceinline__ float wave_sum(float v) {
    #pragma unroll
    for (int off = 32; off; off >>= 1) v += __shfl_xor(v, off, 64);
    return v;
}

__global__ __launch_bounds__(THREADS)
void fused_attn_kernel(const float* __restrict__ features,
                       const float* __restrict__ W,
                       const float* __restrict__ bvec,
                       const float* __restrict__ agent_bias,
                       const float* __restrict__ gamma,
                       const float* __restrict__ beta,
                       float* __restrict__ out_att,   // [B,S,D]
                       float* __restrict__ out_w)     // [B,S,S]
{
    __shared__ __attribute__((aligned(16))) float biasedT[DD][SS]; // [d][t]
    __shared__ __attribute__((aligned(16))) float projT[DD][SS];   // [e][t]
    __shared__ float W_lds[DD * DD];
    __shared__ float b_lds[DD];

    const int tid  = threadIdx.x;
    const int b    = blockIdx.y;
    const int tile = blockIdx.x;

    if (tid < DD * DD) W_lds[tid] = W[tid];
    if (tid < DD)      b_lds[tid] = bvec[tid];

    // ---- stage biased = features + agent_bias, transposed, via coalesced loads
    const float* fbase = features + (size_t)b * (SS * DD);
    #pragma unroll
    for (int k = 0; k < DD; ++k) {
        int idx = k * SS + tid;        // 0 .. 3583, fully coalesced
        float v = fbase[idx];
        int t = idx / DD;              // magic-mul division
        int d = idx - t * DD;
        biasedT[d][t] = v + agent_bias[d];
    }
    __syncthreads();

    // ---- projection: projT[e][t] = b[e] + sum_d biasedT[d][t] * W[e][d]
    {
        float bt[DD];
        #pragma unroll
        for (int d = 0; d < DD; ++d) bt[d] = biasedT[d][tid];
        #pragma unroll
        for (int e = 0; e < DD; ++e) {
            float p = b_lds[e];
            #pragma unroll
            for (int d = 0; d < DD; ++d) p += bt[d] * W_lds[e * DD + d];
            projT[e][tid] = p;
        }
    }
    __syncthreads();

    // ---- one wave per query row
    const int wave = tid >> 6;
    const int lane = tid & 63;
    const int s = tile * ROWS + wave;

    const float RSQRT_D = 0.3779644730092272f;  // 1/sqrt(7)

    float ps[DD];
    #pragma unroll
    for (int d = 0; d < DD; ++d) ps[d] = projT[d][s];  // broadcast read

    // scores for 8 keys per lane: t = c*256 + lane*4 + k
    float sc[8];
    #pragma unroll
    for (int c = 0; c < 2; ++c) {
        const int t0 = c * 256 + lane * 4;
        float4 v = make_float4(0.f, 0.f, 0.f, 0.f);
        #pragma unroll
        for (int d = 0; d < DD; ++d) {
            float4 p = *(const float4*)&projT[d][t0];
            v.x += ps[d] * p.x; v.y += ps[d] * p.y;
            v.z += ps[d] * p.z; v.w += ps[d] * p.w;
        }
        sc[c * 4 + 0] = v.x * RSQRT_D;
        sc[c * 4 + 1] = v.y * RSQRT_D;
        sc[c * 4 + 2] = v.z * RSQRT_D;
        sc[c * 4 + 3] = v.w * RSQRT_D;
    }

    // softmax over 512 keys (8 regs/lane x 64 lanes)
    float m = sc[0];
    #pragma unroll
    for (int k = 1; k < 8; ++k) m = fmaxf(m, sc[k]);
    m = wave_max(m);

    float sum = 0.f;
    #pragma unroll
    for (int k = 0; k < 8; ++k) { sc[k] = __expf(sc[k] - m); sum += sc[k]; }
    sum = wave_sum(sum);
    const float inv = 1.0f / sum;
    #pragma unroll
    for (int k = 0; k < 8; ++k) sc[k] *= inv;

    // coalesced float4 weight stores
    float* wrow = out_w + ((size_t)(b * SS + s)) * SS;
    #pragma unroll
    for (int c = 0; c < 2; ++c) {
        float4 w4 = make_float4(sc[c * 4 + 0], sc[c * 4 + 1],
                                sc[c * 4 + 2], sc[c * 4 + 3]);
        *(float4*)(wrow + c * 256 + lane * 4) = w4;
    }

    // attended[s][d] = sum_t w[t] * biasedT[d][t]
    float acc[DD];
    #pragma unroll
    for (int d = 0; d < DD; ++d) acc[d] = 0.f;
    #pragma unroll
    for (int c = 0; c < 2; ++c) {
        const int t0 = c * 256 + lane * 4;
        #pragma unroll
        for (int d = 0; d < DD; ++d) {
            float4 bt = *(const float4*)&biasedT[d][t0];
            acc[d] += sc[c * 4 + 0] * bt.x + sc[c * 4 + 1] * bt.y
                    + sc[c * 4 + 2] * bt.z + sc[c * 4 + 3] * bt.w;
        }
    }
    #pragma unroll
    for (int off = 32; off; off >>= 1) {
        #pragma unroll
        for (int d = 0; d < DD; ++d) acc[d] += __shfl_xor(acc[d], off, 64);
    }

    // layer norm over D=7 + store (lane 0)
    if (lane == 0) {
        float mu = 0.f;
        #pragma unroll
        for (int d = 0; d < DD; ++d) mu += acc[d];
        mu *= (1.0f / 7.0f);
        float var = 0.f;
        #pragma unroll
        for (int d = 0; d < DD; ++d) { float t = acc[d] - mu; var += t * t; }
        var *= (1.0f / 7.0f);
        const float r = rsqrtf(var + 1e-5f);
        float* orow = out_att + (size_t)(b * SS + s) * DD;
        #pragma unroll
        for (int d = 0; d < DD; ++d)
            orow[d] = (acc[d] - mu) * r * gamma[d] + beta[d];
    }
}

extern "C" void kernel_launch(void* const* d_in, const int* in_sizes, int n_in,
                              void* d_out, int out_size, void* d_ws, size_t ws_size,
                              hipStream_t stream) {
    const float* features   = (const float*)d_in[0];
    const float* W          = (const float*)d_in[1];
    const float* bvec       = (const float*)d_in[2];
    const float* agent_bias = (const float*)d_in[3];
    const float* gamma      = (const float*)d_in[4];
    const float* beta       = (const float*)d_in[5];

    float* out_att = (float*)d_out;                          // [256,512,7]
    float* out_w   = (float*)d_out + (size_t)BB * SS * DD;   // [256,512,512]

    dim3 grid(SS / ROWS, BB);
    fused_attn_kernel<<<grid, THREADS, 0, stream>>>(
        features, W, bvec, agent_bias, gamma, beta, out_att, out_w);
}

// Round 2
// 296.155 us; speedup vs baseline: 1.2796x; 1.2796x over previous
//
#include <hip/hip_runtime.h>
#include <math.h>

#define BB 256
#define SS 512
#define DD 7
#define ROWS_PER_WAVE 8
#define WAVES 4
#define THREADS (WAVES * 64)              // 256
#define ROWS_PER_BLOCK (ROWS_PER_WAVE * WAVES)  // 32
#define QSCALE 0.6147881529512643f        // 7^(-1/4); (QSCALE*QSCALE)=1/sqrt(7)

// ---- DPP wave reductions (VALU pipe, no DS traffic). Result valid in lane 63.
template <int CTRL>
__device__ __forceinline__ float dpp_add(float v) {
    int x = __builtin_amdgcn_update_dpp(0, __float_as_int(v), CTRL, 0xf, 0xf, true);
    return v + __int_as_float(x);
}
template <int CTRL>
__device__ __forceinline__ float dpp_max(float v) {
    // bound_ctrl=false, old = own value -> invalid lanes contribute max(v,v)=v
    int x = __builtin_amdgcn_update_dpp(__float_as_int(v), __float_as_int(v), CTRL, 0xf, 0xf, false);
    return fmaxf(v, __int_as_float(x));
}
__device__ __forceinline__ float wave_sum63(float v) {
    v = dpp_add<0x111>(v);  // row_shr:1
    v = dpp_add<0x112>(v);  // row_shr:2
    v = dpp_add<0x114>(v);  // row_shr:4
    v = dpp_add<0x118>(v);  // row_shr:8
    v = dpp_add<0x142>(v);  // row_bcast:15
    v = dpp_add<0x143>(v);  // row_bcast:31
    return v;
}
__device__ __forceinline__ float wave_max63(float v) {
    v = dpp_max<0x111>(v);
    v = dpp_max<0x112>(v);
    v = dpp_max<0x114>(v);
    v = dpp_max<0x118>(v);
    v = dpp_max<0x142>(v);
    v = dpp_max<0x143>(v);
    return v;
}
__device__ __forceinline__ float bcast63(float v) {
    return __int_as_float(__builtin_amdgcn_readlane(__float_as_int(v), 63));
}

__global__ __launch_bounds__(THREADS)
void fused_attn_kernel(const float* __restrict__ features,
                       const float* __restrict__ W,
                       const float* __restrict__ bvec,
                       const float* __restrict__ agent_bias,
                       const float* __restrict__ gamma,
                       const float* __restrict__ beta,
                       float* __restrict__ out_att,   // [B,S,D]
                       float* __restrict__ out_w)     // [B,S,S]
{
    __shared__ __attribute__((aligned(16))) float projT[DD][SS];    // pre-scaled by 7^-1/4
    __shared__ __attribute__((aligned(16))) float biasedT[DD][SS];
    __shared__ __attribute__((aligned(16))) float raw[SS * DD];     // aliased as att rows in phase 3

    const int tid  = threadIdx.x;
    const int b    = blockIdx.y;
    const int tile = blockIdx.x;

    // ---- phase 0: coalesced global -> flat LDS (bank = idx mod 32, conflict-free)
    const float* fbase = features + (size_t)b * (SS * DD);
    #pragma unroll
    for (int k = 0; k < 14; ++k)
        raw[k * THREADS + tid] = fbase[k * THREADS + tid];
    __syncthreads();

    // ---- phase 1: per-t transpose + bias + projection (W/b/agent_bias are
    //      uniform-address global reads -> scalar loads, no LDS needed)
    #pragma unroll
    for (int h = 0; h < 2; ++h) {
        const int t = h * THREADS + tid;
        float bt[DD];
        #pragma unroll
        for (int d = 0; d < DD; ++d) bt[d] = raw[t * DD + d] + agent_bias[d];
        #pragma unroll
        for (int d = 0; d < DD; ++d) biasedT[d][t] = bt[d];
        #pragma unroll
        for (int e = 0; e < DD; ++e) {
            float p = bvec[e];
            #pragma unroll
            for (int d = 0; d < DD; ++d) p = fmaf(bt[d], W[e * DD + d], p);
            projT[e][t] = p * QSCALE;
        }
    }
    __syncthreads();

    // ---- phase 2: one wave handles 8 rows; key fragments live in registers
    const int wave = tid >> 6;
    const int lane = tid & 63;

    float4 pk4[2][DD];  // proj of this lane's 8 keys (pre-scaled)
    float4 bk4[2][DD];  // biased of this lane's 8 keys
    #pragma unroll
    for (int c = 0; c < 2; ++c) {
        #pragma unroll
        for (int d = 0; d < DD; ++d) {
            pk4[c][d] = *(const float4*)&projT[d][c * 256 + lane * 4];
            bk4[c][d] = *(const float4*)&biasedT[d][c * 256 + lane * 4];
        }
    }

    float* att = raw;  // reuse raw[] (phase-1 reads are behind the barrier)
    const int row0 = wave * ROWS_PER_WAVE;

    #pragma unroll 1
    for (int r = 0; r < ROWS_PER_WAVE; ++r) {
        const int rb = row0 + r;                       // row within block
        const int s  = tile * ROWS_PER_BLOCK + rb;     // row within batch

        float ps[DD];
        #pragma unroll
        for (int d = 0; d < DD; ++d) ps[d] = projT[d][s];   // LDS broadcast

        // scores (pre-scaled: ps*pk already includes 1/sqrt(7))
        float4 sc[2];
        #pragma unroll
        for (int c = 0; c < 2; ++c) {
            float4 v; v.x = v.y = v.z = v.w = 0.f;
            #pragma unroll
            for (int d = 0; d < DD; ++d) {
                v.x = fmaf(ps[d], pk4[c][d].x, v.x);
                v.y = fmaf(ps[d], pk4[c][d].y, v.y);
                v.z = fmaf(ps[d], pk4[c][d].z, v.z);
                v.w = fmaf(ps[d], pk4[c][d].w, v.w);
            }
            sc[c] = v;
        }

        // softmax over 512 keys
        float m = fmaxf(fmaxf(fmaxf(sc[0].x, sc[0].y), fmaxf(sc[0].z, sc[0].w)),
                        fmaxf(fmaxf(sc[1].x, sc[1].y), fmaxf(sc[1].z, sc[1].w)));
        m = bcast63(wave_max63(m));

        float4 e[2];
        #pragma unroll
        for (int c = 0; c < 2; ++c) {
            e[c].x = __expf(sc[c].x - m);
            e[c].y = __expf(sc[c].y - m);
            e[c].z = __expf(sc[c].z - m);
            e[c].w = __expf(sc[c].w - m);
        }
        float sum = ((e[0].x + e[0].y) + (e[0].z + e[0].w))
                  + ((e[1].x + e[1].y) + (e[1].z + e[1].w));
        sum = bcast63(wave_sum63(sum));
        const float inv = __builtin_amdgcn_rcpf(sum);

        float4 w0, w1;
        w0.x = e[0].x * inv; w0.y = e[0].y * inv; w0.z = e[0].z * inv; w0.w = e[0].w * inv;
        w1.x = e[1].x * inv; w1.y = e[1].y * inv; w1.z = e[1].z * inv; w1.w = e[1].w * inv;

        // coalesced weight stores (1 KiB per instruction per wave)
        float* wrow = out_w + ((size_t)(b * SS + s)) * SS;
        *(float4*)(wrow + lane * 4)       = w0;
        *(float4*)(wrow + 256 + lane * 4) = w1;

        // attended partials + DPP reduction (no DS traffic)
        #pragma unroll
        for (int d = 0; d < DD; ++d) {
            float a;
            a = w0.x * bk4[0][d].x;
            a = fmaf(w0.y, bk4[0][d].y, a);
            a = fmaf(w0.z, bk4[0][d].z, a);
            a = fmaf(w0.w, bk4[0][d].w, a);
            a = fmaf(w1.x, bk4[1][d].x, a);
            a = fmaf(w1.y, bk4[1][d].y, a);
            a = fmaf(w1.z, bk4[1][d].z, a);
            a = fmaf(w1.w, bk4[1][d].w, a);
            a = wave_sum63(a);
            if (lane == 63) att[rb * DD + d] = a;
        }
    }
    __syncthreads();

    // ---- phase 3a: LayerNorm per row (first 32 threads, one row each)
    if (tid < ROWS_PER_BLOCK) {
        float a[DD];
        #pragma unroll
        for (int d = 0; d < DD; ++d) a[d] = att[tid * DD + d];
        float mu = 0.f;
        #pragma unroll
        for (int d = 0; d < DD; ++d) mu += a[d];
        mu *= (1.0f / 7.0f);
        float var = 0.f;
        #pragma unroll
        for (int d = 0; d < DD; ++d) { float t = a[d] - mu; var += t * t; }
        var *= (1.0f / 7.0f);
        const float rs = rsqrtf(var + 1e-5f);
        #pragma unroll
        for (int d = 0; d < DD; ++d)
            att[tid * DD + d] = (a[d] - mu) * rs * gamma[d] + beta[d];
    }
    __syncthreads();

    // ---- phase 3b: coalesced attended store (224 contiguous floats)
    if (tid < ROWS_PER_BLOCK * DD) {
        out_att[((size_t)b * SS + tile * ROWS_PER_BLOCK) * DD + tid] = att[tid];
    }
}

extern "C" void kernel_launch(void* const* d_in, const int* in_sizes, int n_in,
                              void* d_out, int out_size, void* d_ws, size_t ws_size,
                              hipStream_t stream) {
    const float* features   = (const float*)d_in[0];
    const float* W          = (const float*)d_in[1];
    const float* bvec       = (const float*)d_in[2];
    const float* agent_bias = (const float*)d_in[3];
    const float* gamma      = (const float*)d_in[4];
    const float* beta       = (const float*)d_in[5];

    float* out_att = (float*)d_out;                          // [256,512,7]
    float* out_w   = (float*)d_out + (size_t)BB * SS * DD;   // [256,512,512]

    dim3 grid(SS / ROWS_PER_BLOCK, BB);                      // (16, 256)
    fused_attn_kernel<<<grid, THREADS, 0, stream>>>(
        features, W, bvec, agent_bias, gamma, beta, out_att, out_w);
}